// Round 1
// baseline (540.467 us; speedup 1.0000x reference)
//
#include <hip/hip_runtime.h>

#define S_LEN 2048
#define DMODEL 1024
#define NH 16
#define NKVH 4
#define DKH 64
#define KVD 256
#define ATT_SCALE 0.125f

typedef __bf16 bf16;
typedef bf16  bf16x8 __attribute__((ext_vector_type(8)));
typedef bf16  bf16x4 __attribute__((ext_vector_type(4)));
typedef float f32x4  __attribute__((ext_vector_type(4)));
typedef bf16x8 bf16x8_a __attribute__((may_alias));
typedef float f32x4g __attribute__((ext_vector_type(4), may_alias));

__device__ __forceinline__ void gll16(const bf16* g, bf16* l) {
    __builtin_amdgcn_global_load_lds(
        (const __attribute__((address_space(1))) void*)g,
        (__attribute__((address_space(3))) void*)l, 16, 0, 0);
}

// ---------------- fp32 -> bf16 cast (vectorized) ----------------
__global__ __launch_bounds__(256) void cast_bf16(const float* __restrict__ in,
                                                 bf16* __restrict__ out, int n4) {
    int stride = gridDim.x * blockDim.x;
    for (int i = blockIdx.x * blockDim.x + threadIdx.x; i < n4; i += stride) {
        f32x4g v = ((const f32x4g*)in)[i];
        bf16x4 o;
        o[0] = (bf16)v[0]; o[1] = (bf16)v[1]; o[2] = (bf16)v[2]; o[3] = (bf16)v[3];
        ((bf16x4*)out)[i] = o;
    }
}

// ---------------- NT GEMM: C[m][n] = sum_k A[m][k]*Bw[n][k] + bias[n] ----------------
// 128x128 tile, BK=32, 4 waves (2x2), each wave 64x64 = 4x4 frags of 16x16.
template <int OUTF32>
__global__ __launch_bounds__(256) void gemm_bt(const bf16* __restrict__ A,
                                               const bf16* __restrict__ Bw,
                                               const float* __restrict__ bias,
                                               void* __restrict__ Cout,
                                               int M, int N, int K) {
    __shared__ bf16 As[4096];  // 128 x 32
    __shared__ bf16 Bs[4096];
    const int bm = blockIdx.x, bn = blockIdx.y;
    const int tid = threadIdx.x, wave = tid >> 6, lane = tid & 63;
    const int l15 = lane & 15, lhi = lane >> 4;
    const int wr = (wave >> 1) * 64, wc = (wave & 1) * 64;
    f32x4 acc[4][4] = {};
    const size_t arow0 = (size_t)bm * 128 * K;
    const size_t brow0 = (size_t)bn * 128 * K;

    for (int kt = 0; kt < K; kt += 32) {
#pragma unroll
        for (int i = 0; i < 2; ++i) {
            int base = i * 2048 + wave * 512;   // elems within the 128x32 tile
            int flat = base + lane * 8;
            int r = flat >> 5, c = flat & 31;
            gll16(A + arow0 + (size_t)r * K + kt + c, &As[base]);
            gll16(Bw + brow0 + (size_t)r * K + kt + c, &Bs[base]);
        }
        __syncthreads();
        bf16x8 af[4], bfr[4];
#pragma unroll
        for (int mi = 0; mi < 4; ++mi)
            af[mi] = *(const bf16x8_a*)&As[(wr + mi * 16 + l15) * 32 + lhi * 8];
#pragma unroll
        for (int ni = 0; ni < 4; ++ni)
            bfr[ni] = *(const bf16x8_a*)&Bs[(wc + ni * 16 + l15) * 32 + lhi * 8];
#pragma unroll
        for (int mi = 0; mi < 4; ++mi)
#pragma unroll
            for (int ni = 0; ni < 4; ++ni)
                acc[mi][ni] = __builtin_amdgcn_mfma_f32_16x16x32_bf16(
                    af[mi], bfr[ni], acc[mi][ni], 0, 0, 0);
        __syncthreads();
    }
    // epilogue: D row=(lane>>4)*4+j, col=lane&15
#pragma unroll
    for (int mi = 0; mi < 4; ++mi)
#pragma unroll
        for (int ni = 0; ni < 4; ++ni)
#pragma unroll
            for (int j = 0; j < 4; ++j) {
                int row = bm * 128 + wr + mi * 16 + lhi * 4 + j;
                int col = bn * 128 + wc + ni * 16 + l15;
                float v = acc[mi][ni][j] + bias[col];
                if (OUTF32)
                    ((float*)Cout)[(size_t)row * N + col] = v;
                else
                    ((bf16*)Cout)[(size_t)row * N + col] = (bf16)v;
            }
}

// ---------------- V transpose: Vp[b*2048+s][g*64+d] -> VT[b][g][d][s] ----------------
__global__ __launch_bounds__(256) void vtrans(const bf16* __restrict__ V,
                                              bf16* __restrict__ VT) {
    __shared__ bf16 t[64][65];
    const int s0 = blockIdx.x * 64;
    const int bg = blockIdx.y;           // b*4+g
    const int b = bg >> 2, g = bg & 3;
#pragma unroll
    for (int i = 0; i < 16; ++i) {
        int flat = threadIdx.x + i * 256;      // 0..4095
        int r = flat >> 6, c = flat & 63;      // r: s offset, c: d
        t[c][r] = V[(size_t)(b * S_LEN + s0 + r) * KVD + g * DKH + c];
    }
    __syncthreads();
#pragma unroll
    for (int i = 0; i < 16; ++i) {
        int flat = threadIdx.x + i * 256;
        int d = flat >> 6, si = flat & 63;
        VT[((size_t)bg * DKH + d) * S_LEN + s0 + si] = t[d][si];
    }
}

// ---------------- fused GQA attention ----------------
// grid: B*NH*(S/64); block: 256 (4 waves x 16 q-rows).
// Two passes over 32 K-tiles of 64 keys: A) softmax denom, B) probs->global + PV.
__global__ __launch_bounds__(256) void attn_fused(const bf16* __restrict__ Qp,  // [B*S][DMODEL]
                                                  const bf16* __restrict__ Kp,  // [B*S][KVD]
                                                  const bf16* __restrict__ VT,  // [B][KVH][DKH][S]
                                                  float* __restrict__ attn_out, // [B][NH][S][S]
                                                  bf16* __restrict__ ctx) {     // [B*S][DMODEL]
    __shared__ bf16 plds[4][1024];  // per-wave 16x64 bf16, XOR-swizzled
    const int bid = blockIdx.x;
    const int qt = bid & 31;
    const int bh = bid >> 5;
    const int h = bh & (NH - 1);
    const int b = bh >> 4;
    const int g = h >> 2;
    const int wave = threadIdx.x >> 6, lane = threadIdx.x & 63;
    const int l15 = lane & 15, lhi = lane >> 4;
    const int qrow0 = qt * 64 + wave * 16;

    // Q fragments (rows fixed for this wave), A-frag: row=l15, k=lhi*8+j
    const bf16* qbase = Qp + (size_t)(b * S_LEN + qrow0 + l15) * DMODEL + h * DKH + lhi * 8;
    bf16x8 aq0 = *(const bf16x8_a*)qbase;
    bf16x8 aq1 = *(const bf16x8_a*)(qbase + 32);

    float lsum[4] = {0.f, 0.f, 0.f, 0.f};

    // ---- pass A: softmax denominators (no max subtraction; |logit| <= ~10) ----
    for (int kt = 0; kt < S_LEN / 64; ++kt) {
        const int key0 = kt * 64;
        const bf16* kbase = Kp + (size_t)(b * S_LEN + key0 + l15) * KVD + g * DKH + lhi * 8;
        f32x4 s[4];
#pragma unroll
        for (int nt = 0; nt < 4; ++nt) {
            bf16x8 k0 = *(const bf16x8_a*)(kbase + (size_t)nt * 16 * KVD);
            bf16x8 k1 = *(const bf16x8_a*)(kbase + (size_t)nt * 16 * KVD + 32);
            f32x4 a = {0.f, 0.f, 0.f, 0.f};
            a = __builtin_amdgcn_mfma_f32_16x16x32_bf16(aq0, k0, a, 0, 0, 0);
            a = __builtin_amdgcn_mfma_f32_16x16x32_bf16(aq1, k1, a, 0, 0, 0);
            s[nt] = a;
        }
#pragma unroll
        for (int j = 0; j < 4; ++j) {
            float e = __expf(s[0][j] * ATT_SCALE) + __expf(s[1][j] * ATT_SCALE) +
                      __expf(s[2][j] * ATT_SCALE) + __expf(s[3][j] * ATT_SCALE);
            e += __shfl_xor(e, 1, 64);
            e += __shfl_xor(e, 2, 64);
            e += __shfl_xor(e, 4, 64);
            e += __shfl_xor(e, 8, 64);
            lsum[j] += e;
        }
    }
    float rinv[4];
#pragma unroll
    for (int j = 0; j < 4; ++j) rinv[j] = 1.0f / lsum[j];

    // ---- pass B: write probs + accumulate ctx ----
    f32x4 cacc[4] = {};
    float* arow = attn_out + ((size_t)(bh)*S_LEN + qrow0) * S_LEN;
    char* pl = (char*)&plds[wave][0];
    for (int kt = 0; kt < S_LEN / 64; ++kt) {
        const int key0 = kt * 64;
        const bf16* kbase = Kp + (size_t)(b * S_LEN + key0 + l15) * KVD + g * DKH + lhi * 8;
        f32x4 s[4];
#pragma unroll
        for (int nt = 0; nt < 4; ++nt) {
            bf16x8 k0 = *(const bf16x8_a*)(kbase + (size_t)nt * 16 * KVD);
            bf16x8 k1 = *(const bf16x8_a*)(kbase + (size_t)nt * 16 * KVD + 32);
            f32x4 a = {0.f, 0.f, 0.f, 0.f};
            a = __builtin_amdgcn_mfma_f32_16x16x32_bf16(aq0, k0, a, 0, 0, 0);
            a = __builtin_amdgcn_mfma_f32_16x16x32_bf16(aq1, k1, a, 0, 0, 0);
            s[nt] = a;
        }
        // probs: global fp32 write + swizzled LDS bf16 write (per-wave region)
#pragma unroll
        for (int nt = 0; nt < 4; ++nt)
#pragma unroll
            for (int j = 0; j < 4; ++j) {
                float p = __expf(s[nt][j] * ATT_SCALE) * rinv[j];
                arow[(size_t)(lhi * 4 + j) * S_LEN + key0 + nt * 16 + l15] = p;
                int r = lhi * 4 + j, c = nt * 16 + l15;
                int byte = (r * 128 + c * 2) ^ ((r & 7) << 4);
                *(bf16*)(pl + byte) = (bf16)p;
            }
        // P A-fragments (same wave wrote them; compiler orders via lgkmcnt)
        bf16x8 ap0, ap1;
        {
            int r = l15;
            int byte0 = (r * 128 + (lhi * 8) * 2) ^ ((r & 7) << 4);
            int byte1 = (r * 128 + (32 + lhi * 8) * 2) ^ ((r & 7) << 4);
            ap0 = *(const bf16x8_a*)(pl + byte0);
            ap1 = *(const bf16x8_a*)(pl + byte1);
        }
        const bf16* vbase = VT + ((size_t)(b * NKVH + g)) * DKH * S_LEN + key0 + lhi * 8;
#pragma unroll
        for (int nt = 0; nt < 4; ++nt) {
            bf16x8 v0 = *(const bf16x8_a*)(vbase + (size_t)(nt * 16 + l15) * S_LEN);
            bf16x8 v1 = *(const bf16x8_a*)(vbase + (size_t)(nt * 16 + l15) * S_LEN + 32);
            cacc[nt] = __builtin_amdgcn_mfma_f32_16x16x32_bf16(ap0, v0, cacc[nt], 0, 0, 0);
            cacc[nt] = __builtin_amdgcn_mfma_f32_16x16x32_bf16(ap1, v1, cacc[nt], 0, 0, 0);
        }
    }
    // write ctx (bf16) at [b*S+row][h*64 + d]
#pragma unroll
    for (int nt = 0; nt < 4; ++nt)
#pragma unroll
        for (int j = 0; j < 4; ++j) {
            int row = qrow0 + lhi * 4 + j;
            ctx[(size_t)(b * S_LEN + row) * DMODEL + h * DKH + nt * 16 + l15] =
                (bf16)cacc[nt][j];
        }
}

extern "C" void kernel_launch(void* const* d_in, const int* in_sizes, int n_in,
                              void* d_out, int out_size, void* d_ws, size_t ws_size,
                              hipStream_t stream) {
    const float* query = (const float*)d_in[0];
    const float* key_i = (const float*)d_in[1];
    const float* value = (const float*)d_in[2];
    const float* Wq = (const float*)d_in[3];
    const float* bq = (const float*)d_in[4];
    const float* Wk = (const float*)d_in[5];
    const float* bk = (const float*)d_in[6];
    const float* Wv = (const float*)d_in[7];
    const float* bv = (const float*)d_in[8];
    const float* Wo = (const float*)d_in[9];
    const float* bo = (const float*)d_in[10];

    char* ws = (char*)d_ws;
    // layout (bytes); qx reused as ctx, kx reused as VT (safe: sequential stream)
    bf16* qx = (bf16*)(ws + 0);          // 4096x1024  (8 MB)   later: ctx
    bf16* kx = (bf16*)(ws + 8388608);    // 4096x1024  (8 MB)   later: VT (2 MB)
    bf16* vx = (bf16*)(ws + 16777216);   // 4096x1024  (8 MB)
    bf16* wqx = (bf16*)(ws + 25165824);  // 1024x1024  (2 MB)
    bf16* wkx = (bf16*)(ws + 27262976);  // 256x1024   (0.5 MB)
    bf16* wvx = (bf16*)(ws + 27787264);  // 256x1024   (0.5 MB)
    bf16* wox = (bf16*)(ws + 28311552);  // 1024x1024  (2 MB)
    bf16* Qp = (bf16*)(ws + 30408704);   // 4096x1024  (8 MB)
    bf16* Kp = (bf16*)(ws + 38797312);   // 4096x256   (2 MB)
    bf16* Vp = (bf16*)(ws + 40894464);   // 4096x256   (2 MB)
    bf16* ctx = qx;
    bf16* VT = kx;

    const int BS = 2 * S_LEN;  // 4096 rows

    // casts
    cast_bf16<<<1024, 256, 0, stream>>>(query, qx, BS * DMODEL / 4);
    cast_bf16<<<1024, 256, 0, stream>>>(key_i, kx, BS * DMODEL / 4);
    cast_bf16<<<1024, 256, 0, stream>>>(value, vx, BS * DMODEL / 4);
    cast_bf16<<<1024, 256, 0, stream>>>(Wq, wqx, DMODEL * DMODEL / 4);
    cast_bf16<<<256, 256, 0, stream>>>(Wk, wkx, KVD * DMODEL / 4);
    cast_bf16<<<256, 256, 0, stream>>>(Wv, wvx, KVD * DMODEL / 4);
    cast_bf16<<<1024, 256, 0, stream>>>(Wo, wox, DMODEL * DMODEL / 4);

    // projections
    gemm_bt<0><<<dim3(32, 8), 256, 0, stream>>>(qx, wqx, bq, Qp, BS, DMODEL, DMODEL);
    gemm_bt<0><<<dim3(32, 2), 256, 0, stream>>>(kx, wkx, bk, Kp, BS, KVD, DMODEL);
    gemm_bt<0><<<dim3(32, 2), 256, 0, stream>>>(vx, wvx, bv, Vp, BS, KVD, DMODEL);

    // V transpose -> [b][g][d][s]
    vtrans<<<dim3(32, 8), 256, 0, stream>>>(Vp, VT);

    // fused attention: probs -> d_out tail, ctx -> ws
    float* attn_out = (float*)d_out + (size_t)BS * DMODEL;
    attn_fused<<<2 * NH * (S_LEN / 64), 256, 0, stream>>>(Qp, Kp, VT, attn_out, ctx);

    // output projection -> d_out head (fp32)
    gemm_bt<1><<<dim3(32, 8), 256, 0, stream>>>(ctx, wox, bo, (float*)d_out, BS, DMODEL, DMODEL);
}